// Round 4
// baseline (233.283 us; speedup 1.0000x reference)
//
#include <hip/hip_runtime.h>

// AdaptiveAngleConv round 4: implicit-GEMM bf16 MFMA, barrier-free K-loop.
// Canonical-W: all waves read the SAME 72 KB weight block (L1-deduped);
// wave of angle a pairs weight-tap s with x-tap INV_a[s] (baked into BOFF_d).
// Block: 512 thr = 8 waves = (angle 0..3) x (row 0..1); tile M=256 x N=128.
// Wave tile: M=64 x N=64 (mf=2, nf=2) -> acc 64 AGPRs. 32x32x16 MFMA.

#define CIN 64
#define COUT 64
#define HH 128
#define WW 128
#define NB 16

typedef short bf16x8 __attribute__((ext_vector_type(8)));
typedef float f32x16 __attribute__((ext_vector_type(16)));

// xs LDS layout (R2-proven, 0 conflicts): byte(r, ci, wI) =
//   r*XS_ROW + (ci>>3)*XS_SLOT + wI*16 + (ci&7)*2 ; wI = 0..65 maps w0-1..w0+64
#define XS_SLOT 1072
#define XS_ROW  8576
// total 4*8576 = 34304 B

// BOFF_d[a][s] = dh*XS_ROW + dw*16 for t = INV_a[s] (x-tap paired with weight-tap s)
__device__ __constant__ unsigned BOFF_d[4][9] = {
  {0,16,32,8576,8592,8608,17152,17168,17184},
  {16,32,8608,0,8592,17184,8576,17152,17168},
  {32,8608,17184,16,8592,17168,0,8576,17152},
  {8608,17184,17168,32,8592,17152,16,0,8576},
};

static __device__ __forceinline__ unsigned short f2bf(float f) {
  unsigned u = __builtin_bit_cast(unsigned, f);
  unsigned r = (u + 0x7FFFu + ((u >> 16) & 1u)) >> 16;
  return (unsigned short)r;
}

// Canonical A: e = ((kc*2 + half)*64 + cm)*8 + j ; kc = s*4+q ; ci = q*16 + half*8 + j
// value = W[cm][ci][s].  36864 elements (72 KB bf16).
__global__ void build_A_kernel(const float* __restrict__ wgt,
                               unsigned short* __restrict__ A) {
  const int e = blockIdx.x * 256 + threadIdx.x;
  const int j = e & 7;
  const int cm = (e >> 3) & 63;
  const int half = (e >> 9) & 1;
  const int kc = e >> 10;            // 0..35
  const int s = kc >> 2, q = kc & 3;
  const int ci = q * 16 + half * 8 + j;
  A[e] = f2bf(wgt[(cm * CIN + ci) * 9 + s]);
}

__global__ __launch_bounds__(512, 3) void aconv_mfma4_kernel(
    const float* __restrict__ x,              // [B][CIN][H][W] fp32
    const unsigned short* __restrict__ Ag,    // canonical W, 36864 bf16
    const float* __restrict__ bias,           // [COUT]
    float* __restrict__ out)                  // [4][B][COUT][H][W] fp32
{
  __shared__ __align__(16) unsigned char xs[4 * XS_ROW];

  const int tid = threadIdx.x;
  const int lane = tid & 63;
  const int wid = tid >> 6;         // 8 waves
  const int a   = wid >> 1;         // angle
  const int row = wid & 1;          // output row within 2-row tile
  const int half = lane >> 5;
  const int ln = lane & 31;

  int bid = blockIdx.x;
  const int wh = bid & 1;
  const int hp = (bid >> 1) & 63;
  const int b  = bid >> 7;
  const int w0 = wh * 64;
  const int h0 = hp * 2;

  // ---- stage x tile: 2112 granules of 16 B (8 ci x 1 w each) ----
  #pragma unroll
  for (int i = 0; i < 5; ++i) {
    const int g = tid + i * 512;
    if (g < 2112) {
      const int r    = g / 528;
      const int rest = g - r * 528;
      const int slot = rest / 66;
      const int wI   = rest - slot * 66;
      const int gh = h0 - 1 + r;
      const int gw = w0 - 1 + wI;
      uint4 u4 = {0u, 0u, 0u, 0u};
      if (gh >= 0 && gh < HH && gw >= 0 && gw < WW) {
        const float* xp = x + ((size_t)(b * CIN + slot * 8) * HH + gh) * WW + gw;
        unsigned short v[8];
        #pragma unroll
        for (int q = 0; q < 8; ++q) v[q] = f2bf(xp[(size_t)q * HH * WW]);
        u4.x = (unsigned)v[0] | ((unsigned)v[1] << 16);
        u4.y = (unsigned)v[2] | ((unsigned)v[3] << 16);
        u4.z = (unsigned)v[4] | ((unsigned)v[5] << 16);
        u4.w = (unsigned)v[6] | ((unsigned)v[7] << 16);
      }
      *(uint4*)(xs + (unsigned)(r * XS_ROW + slot * XS_SLOT + wI * 16)) = u4;
    }
  }
  __syncthreads();

  // ---- K-loop: 36 steps of K=16, no barriers, 1-deep prefetch ----
  f32x16 acc[2][2];
  #pragma unroll
  for (int mf = 0; mf < 2; ++mf)
    #pragma unroll
    for (int nf = 0; nf < 2; ++nf) acc[mf][nf] = (f32x16)(0.f);

  const unsigned char* Abase = (const unsigned char*)Ag + (unsigned)(half * 64 + ln) * 16;
  const unsigned char* Bbase = xs + (unsigned)(row * XS_ROW + half * XS_SLOT + ln * 16);
  const unsigned* boffA = BOFF_d[a];

  bf16x8 a0 = *(const bf16x8*)(Abase);
  bf16x8 a1 = *(const bf16x8*)(Abase + 512);
  bf16x8 b0 = *(const bf16x8*)(Bbase + boffA[0]);
  bf16x8 b1 = *(const bf16x8*)(Bbase + boffA[0] + 512);

  #pragma unroll
  for (int kc = 0; kc < 36; ++kc) {
    bf16x8 na0, na1, nb0, nb1;
    if (kc < 35) {
      const int kn = kc + 1;
      const unsigned ab = (unsigned)kn * 2048;
      na0 = *(const bf16x8*)(Abase + ab);
      na1 = *(const bf16x8*)(Abase + ab + 512);
      const unsigned bb = boffA[kn >> 2] + (unsigned)((kn & 3) * 2) * XS_SLOT;
      nb0 = *(const bf16x8*)(Bbase + bb);
      nb1 = *(const bf16x8*)(Bbase + bb + 512);
    }
    acc[0][0] = __builtin_amdgcn_mfma_f32_32x32x16_bf16(a0, b0, acc[0][0], 0, 0, 0);
    acc[0][1] = __builtin_amdgcn_mfma_f32_32x32x16_bf16(a0, b1, acc[0][1], 0, 0, 0);
    acc[1][0] = __builtin_amdgcn_mfma_f32_32x32x16_bf16(a1, b0, acc[1][0], 0, 0, 0);
    acc[1][1] = __builtin_amdgcn_mfma_f32_32x32x16_bf16(a1, b1, acc[1][1], 0, 0, 0);
    a0 = na0; a1 = na1; b0 = nb0; b1 = nb1;
  }

  // ---- epilogue: bias + store ----
  #pragma unroll
  for (int mf = 0; mf < 2; ++mf) {
    #pragma unroll
    for (int nf = 0; nf < 2; ++nf) {
      const f32x16 v = acc[mf][nf];
      #pragma unroll
      for (int g = 0; g < 16; ++g) {
        const int rowc = (g & 3) + 8 * (g >> 2) + 4 * half;
        const int co = mf * 32 + rowc;
        const size_t o = (((size_t)(a * NB + b) * COUT + co) * HH + (h0 + row)) * WW
                         + (w0 + nf * 32 + ln);
        out[o] = v[g] + bias[co];
      }
    }
  }
}

extern "C" void kernel_launch(void* const* d_in, const int* in_sizes, int n_in,
                              void* d_out, int out_size, void* d_ws, size_t ws_size,
                              hipStream_t stream) {
  const float* x    = (const float*)d_in[0];
  const float* wgt  = (const float*)d_in[1];
  const float* bias = (const float*)d_in[2];
  float* out = (float*)d_out;
  unsigned short* A = (unsigned short*)d_ws;   // 73,728 B

  build_A_kernel<<<144, 256, 0, stream>>>(wgt, A);
  aconv_mfma4_kernel<<<NB * (HH/2) * (WW/64), 512, 0, stream>>>(x, A, bias, out);
}

// Round 5
// 107.705 us; speedup vs baseline: 2.1660x; 2.1660x over previous
//
#include <hip/hip_runtime.h>

// AdaptiveAngleConv round 5: persistent implicit-GEMM bf16 MFMA, pure-LDS K-loop.
// 256 blocks x 512 thr (1/CU); each block: canonical A (72 KB) in LDS once,
// then 8 spatial tiles (2 rows x 64 w), x staged per tile with issue-early/
// write-late (T14). Waves = (angle 0..3) x (row 0..1); wave tile M=64 x N=64.

#define CIN 64
#define COUT 64
#define HH 128
#define WW 128
#define NB 16

typedef short bf16x8 __attribute__((ext_vector_type(8)));
typedef float f32x16 __attribute__((ext_vector_type(16)));

// xs layout (proven 0-conflict): byte(r, ci, wI) = r*XS_ROW + (ci>>3)*XS_SLOT + wI*16 + (ci&7)*2
#define XS_SLOT 1072
#define XS_ROW  8576
#define XS_OFF  73728
#define LDS_BYTES (XS_OFF + 4 * XS_ROW)   // 108,032 B

// BOFF_d[a][s] = dh*XS_ROW + dw*16 for x-tap INV_a[s] paired with weight-tap s (R4-validated)
__device__ __constant__ unsigned BOFF_d[4][9] = {
  {0,16,32,8576,8592,8608,17152,17168,17184},
  {16,32,8608,0,8592,17184,8576,17152,17168},
  {32,8608,17184,16,8592,17168,0,8576,17152},
  {8608,17184,17168,32,8592,17152,16,0,8576},
};

static __device__ __forceinline__ unsigned short f2bf(float f) {
  unsigned u = __builtin_bit_cast(unsigned, f);
  unsigned r = (u + 0x7FFFu + ((u >> 16) & 1u)) >> 16;
  return (unsigned short)r;
}

// Canonical A (R4-validated): e = ((kc*2 + half)*64 + cm)*8 + j ; kc = s*4+q ;
// ci = q*16 + half*8 + j ; value = W[cm][ci][s]. 72 KB bf16.
__global__ void build_A_kernel(const float* __restrict__ wgt,
                               unsigned short* __restrict__ A) {
  const int e = blockIdx.x * 256 + threadIdx.x;
  const int j = e & 7;
  const int cm = (e >> 3) & 63;
  const int half = (e >> 9) & 1;
  const int kc = e >> 10;            // 0..35
  const int s = kc >> 2, q = kc & 3;
  const int ci = q * 16 + half * 8 + j;
  A[e] = f2bf(wgt[(cm * CIN + ci) * 9 + s]);
}

__global__ __launch_bounds__(512) void aconv_persist_kernel(
    const float* __restrict__ x,              // [B][CIN][H][W] fp32
    const unsigned short* __restrict__ Ag,    // canonical W, 36864 bf16
    const float* __restrict__ bias,           // [COUT]
    float* __restrict__ out)                  // [4][B][COUT][H][W] fp32
{
  __shared__ __align__(16) unsigned char lds[LDS_BYTES];

  const int tid = threadIdx.x;
  const int lane = tid & 63;
  const int wid = tid >> 6;
  const int a   = wid >> 1;         // angle
  const int row = wid & 1;          // output row within 2-row tile
  const int half = lane >> 5;
  const int ln = lane & 31;

  const int blk = blockIdx.x;       // 256 blocks
  const int b   = blk >> 4;         // batch
  const int rem = blk & 15;         // hp-group: hp = rem*4 + (it>>1)

  // ---- bias fragments (co = mf*32 + (g&3)+8*(g>>2)+4*half) ----
  float bv[2][16];
  #pragma unroll
  for (int mf = 0; mf < 2; ++mf)
    #pragma unroll
    for (int g = 0; g < 16; ++g)
      bv[mf][g] = bias[mf * 32 + (g & 3) + 8 * (g >> 2) + 4 * half];

  unsigned boff[9];
  #pragma unroll
  for (int s = 0; s < 9; ++s) boff[s] = BOFF_d[a][s];

  // ---- stage canonical A into LDS (72 KB, once per block) ----
  {
    const uint4* Ag4 = (const uint4*)Ag;
    uint4* As4 = (uint4*)lds;
    #pragma unroll
    for (int i = 0; i < 9; ++i)
      As4[tid + i * 512] = Ag4[tid + i * 512];
  }

  // ---- per-thread staging granule geometry (tile-independent) ----
  int grr[5], gwI[5]; unsigned gdst[5]; const float* gxb[5];
  #pragma unroll
  for (int i = 0; i < 5; ++i) {
    const int g = tid + i * 512;               // 2112 granules total
    const int gg = (g < 2112) ? g : 0;
    const int r = gg / 528;
    const int rest = gg - r * 528;
    const int slot = rest / 66;
    const int wI = rest - slot * 66;
    grr[i] = r; gwI[i] = wI;
    gdst[i] = (unsigned)(r * XS_ROW + slot * XS_SLOT + wI * 16);
    gxb[i] = x + (size_t)(b * CIN + slot * 8) * (HH * WW);
  }

  float gxv[5][8];

  // ---- stage tile 0 synchronously ----
  {
    const int h0 = (rem * 4) * 2;
    const int w0 = 0;
    #pragma unroll
    for (int i = 0; i < 5; ++i) {
      const int g = tid + i * 512;
      const int gh = h0 - 1 + grr[i];
      const int gw = w0 - 1 + gwI[i];
      const bool inb = (g < 2112) && (gh >= 0) && (gh < HH) && (gw >= 0) && (gw < WW);
      const float* xp = gxb[i] + gh * WW + gw;
      #pragma unroll
      for (int q = 0; q < 8; ++q)
        gxv[i][q] = inb ? xp[q * (HH * WW)] : 0.f;
    }
    #pragma unroll
    for (int i = 0; i < 5; ++i)
      if (tid + i * 512 < 2112) {
        uint4 u4;
        u4.x = (unsigned)f2bf(gxv[i][0]) | ((unsigned)f2bf(gxv[i][1]) << 16);
        u4.y = (unsigned)f2bf(gxv[i][2]) | ((unsigned)f2bf(gxv[i][3]) << 16);
        u4.z = (unsigned)f2bf(gxv[i][4]) | ((unsigned)f2bf(gxv[i][5]) << 16);
        u4.w = (unsigned)f2bf(gxv[i][6]) | ((unsigned)f2bf(gxv[i][7]) << 16);
        *(uint4*)(lds + XS_OFF + gdst[i]) = u4;
      }
  }
  __syncthreads();

  const unsigned char* Asb = lds + (unsigned)(half * 1024 + ln * 16);
  const unsigned char* Bsb = lds + XS_OFF + (unsigned)(row * XS_ROW + half * XS_SLOT + ln * 16);

  for (int it = 0; it < 8; ++it) {
    const int h0 = (rem * 4 + (it >> 1)) * 2;
    const int w0 = (it & 1) * 64;

    // issue next tile's global loads (consumed after the barrier -> latency hidden)
    if (it < 7) {
      const int itn = it + 1;
      const int h0n = (rem * 4 + (itn >> 1)) * 2;
      const int w0n = (itn & 1) * 64;
      #pragma unroll
      for (int i = 0; i < 5; ++i) {
        const int g = tid + i * 512;
        const int gh = h0n - 1 + grr[i];
        const int gw = w0n - 1 + gwI[i];
        const bool inb = (g < 2112) && (gh >= 0) && (gh < HH) && (gw >= 0) && (gw < WW);
        const float* xp = gxb[i] + gh * WW + gw;
        #pragma unroll
        for (int q = 0; q < 8; ++q)
          gxv[i][q] = inb ? xp[q * (HH * WW)] : 0.f;
      }
    }

    // acc init with bias
    f32x16 acc[2][2];
    #pragma unroll
    for (int mf = 0; mf < 2; ++mf)
      #pragma unroll
      for (int nf = 0; nf < 2; ++nf)
        #pragma unroll
        for (int g = 0; g < 16; ++g)
          acc[mf][nf][g] = bv[mf][g];

    // pure-LDS K-loop: 36 steps of K=16
    #pragma unroll
    for (int kc = 0; kc < 36; ++kc) {
      const int s = kc >> 2, q = kc & 3;
      const bf16x8 af0 = *(const bf16x8*)(Asb + kc * 2048);
      const bf16x8 af1 = *(const bf16x8*)(Asb + kc * 2048 + 512);
      const unsigned bb = boff[s] + (unsigned)(q * 2 * XS_SLOT);
      const bf16x8 bf0 = *(const bf16x8*)(Bsb + bb);
      const bf16x8 bf1 = *(const bf16x8*)(Bsb + bb + 512);
      acc[0][0] = __builtin_amdgcn_mfma_f32_32x32x16_bf16(af0, bf0, acc[0][0], 0, 0, 0);
      acc[0][1] = __builtin_amdgcn_mfma_f32_32x32x16_bf16(af0, bf1, acc[0][1], 0, 0, 0);
      acc[1][0] = __builtin_amdgcn_mfma_f32_32x32x16_bf16(af1, bf0, acc[1][0], 0, 0, 0);
      acc[1][1] = __builtin_amdgcn_mfma_f32_32x32x16_bf16(af1, bf1, acc[1][1], 0, 0, 0);
    }

    // stores (bias already folded into acc init)
    #pragma unroll
    for (int mf = 0; mf < 2; ++mf)
      #pragma unroll
      for (int nf = 0; nf < 2; ++nf) {
        const f32x16 v = acc[mf][nf];
        float* op = out + (((size_t)(a * NB + b) * COUT + mf * 32 + 4 * half) * HH
                           + (h0 + row)) * WW + w0 + nf * 32 + ln;
        #pragma unroll
        for (int g = 0; g < 16; ++g) {
          const int rowc = (g & 3) + 8 * (g >> 2);
          op[(size_t)rowc * (HH * WW)] = v[g];
        }
      }

    __syncthreads();                 // all waves done reading xs
    if (it < 7) {
      #pragma unroll
      for (int i = 0; i < 5; ++i)
        if (tid + i * 512 < 2112) {
          uint4 u4;
          u4.x = (unsigned)f2bf(gxv[i][0]) | ((unsigned)f2bf(gxv[i][1]) << 16);
          u4.y = (unsigned)f2bf(gxv[i][2]) | ((unsigned)f2bf(gxv[i][3]) << 16);
          u4.z = (unsigned)f2bf(gxv[i][4]) | ((unsigned)f2bf(gxv[i][5]) << 16);
          u4.w = (unsigned)f2bf(gxv[i][6]) | ((unsigned)f2bf(gxv[i][7]) << 16);
          *(uint4*)(lds + XS_OFF + gdst[i]) = u4;
        }
    }
    __syncthreads();                 // xs ready for next tile
  }
}

extern "C" void kernel_launch(void* const* d_in, const int* in_sizes, int n_in,
                              void* d_out, int out_size, void* d_ws, size_t ws_size,
                              hipStream_t stream) {
  const float* x    = (const float*)d_in[0];
  const float* wgt  = (const float*)d_in[1];
  const float* bias = (const float*)d_in[2];
  float* out = (float*)d_out;
  unsigned short* A = (unsigned short*)d_ws;   // 73,728 B

  build_A_kernel<<<144, 256, 0, stream>>>(wgt, A);
  aconv_persist_kernel<<<256, 512, 0, stream>>>(x, A, bias, out);
}